// Round 1
// baseline (993.462 us; speedup 1.0000x reference)
//
#include <hip/hip_runtime.h>

typedef __attribute__((ext_vector_type(8))) short bf16x8;   // 8 bf16 in 4 VGPRs
typedef __attribute__((ext_vector_type(4))) float f32x4;

__device__ __forceinline__ short f2bf(float f) {
    // round-to-nearest-even fp32 -> bf16 bits
    union { float f; unsigned u; } v; v.f = f;
    unsigned r = v.u + 0x7FFFu + ((v.u >> 16) & 1u);
    return (short)(r >> 16);
}

#define BATCH      20000
#define NBLK_NEIGH 5000     // 4 waves/block, one b per wave
#define NBLK_SELF  1252     // 313 b-blocks (64 rows) x 4 o-blocks (128 cols)

extern "C" __global__ void __launch_bounds__(256)
fused_aggr(const float* __restrict__ self_vecs,
           const float* __restrict__ neigh,
           const float* __restrict__ W1,
           const float* __restrict__ b1,
           const float* __restrict__ Wt1,
           const float* __restrict__ bt1,
           const float* __restrict__ Wt2,
           const float* __restrict__ bt2,
           float* __restrict__ out)
{
    if ((int)blockIdx.x < NBLK_NEIGH) {
        // ---------------- neighbor path: relu(neigh @ W1 + b1) -> maxpool -> @Wt1 + bt1
        const int lane = threadIdx.x & 63;
        const int wv   = threadIdx.x >> 6;
        const int b    = blockIdx.x * 4 + wv;          // one b per wave
        const int hc   = lane & 15;                    // A-row m / B-col n / C-col
        const int quad = lane >> 4;

        // Preload W1 B-fragments: B[k][n=hc], k = s*32 + quad*8 + j, pad h>=10 with 0
        bf16x8 wf[8];
        #pragma unroll
        for (int s = 0; s < 8; ++s) {
            bf16x8 v;
            #pragma unroll
            for (int j = 0; j < 8; ++j) {
                int k = s * 32 + quad * 8 + j;
                float w = (hc < 10) ? W1[k * 10 + hc] : 0.0f;
                v[j] = f2bf(w);
            }
            wf[s] = v;
        }

        f32x4 c0 = {0.f, 0.f, 0.f, 0.f};
        f32x4 c1 = {0.f, 0.f, 0.f, 0.f};
        const float* row0 = neigh + (long)(b * 32 + hc) * 256;       // n = 0..15 tile
        const float* row1 = row0 + 16 * 256;                         // n = 16..31 tile
        #pragma unroll
        for (int s = 0; s < 8; ++s) {
            const int off = s * 32 + quad * 8;
            float4 xa = *(const float4*)(row0 + off);
            float4 xb = *(const float4*)(row0 + off + 4);
            bf16x8 a;
            a[0]=f2bf(xa.x); a[1]=f2bf(xa.y); a[2]=f2bf(xa.z); a[3]=f2bf(xa.w);
            a[4]=f2bf(xb.x); a[5]=f2bf(xb.y); a[6]=f2bf(xb.z); a[7]=f2bf(xb.w);
            c0 = __builtin_amdgcn_mfma_f32_16x16x32_bf16(a, wf[s], c0, 0, 0, 0);
            float4 ya = *(const float4*)(row1 + off);
            float4 yb = *(const float4*)(row1 + off + 4);
            bf16x8 a2;
            a2[0]=f2bf(ya.x); a2[1]=f2bf(ya.y); a2[2]=f2bf(ya.z); a2[3]=f2bf(ya.w);
            a2[4]=f2bf(yb.x); a2[5]=f2bf(yb.y); a2[6]=f2bf(yb.z); a2[7]=f2bf(yb.w);
            c1 = __builtin_amdgcn_mfma_f32_16x16x32_bf16(a2, wf[s], c1, 0, 0, 0);
        }

        // bias + relu + maxpool over n. relu(x)=max(x,0) and max over n commute:
        // init mx=0 and max the raw biased values (C/D: col=lane&15, row=quad*4+reg).
        const float bias = (hc < 10) ? b1[hc] : 0.0f;
        float mx = 0.0f;
        #pragma unroll
        for (int i = 0; i < 4; ++i) {
            mx = fmaxf(mx, c0[i] + bias);
            mx = fmaxf(mx, c1[i] + bias);
        }
        mx = fmaxf(mx, __shfl_xor(mx, 16));
        mx = fmaxf(mx, __shfl_xor(mx, 32));   // all lanes now hold pooled for their col

        float p[10];
        #pragma unroll
        for (int h = 0; h < 10; ++h) p[h] = __shfl(mx, h);   // lanes 0..9 hold pooled[0..9]

        // from_neighs = pooled @ Wt1 + bt1  -> out[b, 512..1023]
        float* ob = out + (long)b * 1024 + 512;
        #pragma unroll
        for (int i = 0; i < 8; ++i) {
            const int o = lane + i * 64;
            float acc = bt1[o];
            #pragma unroll
            for (int h = 0; h < 10; ++h) acc += p[h] * Wt1[h * 512 + o];
            ob[o] = acc;
        }
    } else {
        // ---------------- self path: self_vecs @ Wt2 + bt2 -> out[b, 0..511]
        const int sb   = blockIdx.x - NBLK_NEIGH;      // 0..1251
        const int bblk = sb >> 2;                      // 0..312  (64 rows each)
        const int oblk = sb & 3;                       // 0..3    (128 cols each)
        const int t  = threadIdx.x;
        const int bt = t >> 5;                         // 0..7
        const int ot = t & 31;                         // 0..31
        const int b0 = bblk * 64 + bt * 8;             // this thread: rows b0..b0+7
        const int o  = oblk * 128 + ot * 4;            // cols o..o+3
        const int oq = o >> 2;

        const float4* self4 = (const float4*)self_vecs;
        const float4* Wt24  = (const float4*)Wt2;

        float4 acc[8];
        int rows[8];
        #pragma unroll
        for (int j = 0; j < 8; ++j) {
            acc[j].x = acc[j].y = acc[j].z = acc[j].w = 0.0f;
            int r = b0 + j;
            rows[j] = (r < BATCH) ? r : (BATCH - 1);   // clamp; store is guarded
        }

        for (int k4 = 0; k4 < 64; ++k4) {
            float4 sv[8];
            #pragma unroll
            for (int j = 0; j < 8; ++j) sv[j] = self4[rows[j] * 64 + k4];

            float4 w;
            w = Wt24[(k4 * 4 + 0) * 128 + oq];
            #pragma unroll
            for (int j = 0; j < 8; ++j) { float s = sv[j].x;
                acc[j].x += s * w.x; acc[j].y += s * w.y; acc[j].z += s * w.z; acc[j].w += s * w.w; }
            w = Wt24[(k4 * 4 + 1) * 128 + oq];
            #pragma unroll
            for (int j = 0; j < 8; ++j) { float s = sv[j].y;
                acc[j].x += s * w.x; acc[j].y += s * w.y; acc[j].z += s * w.z; acc[j].w += s * w.w; }
            w = Wt24[(k4 * 4 + 2) * 128 + oq];
            #pragma unroll
            for (int j = 0; j < 8; ++j) { float s = sv[j].z;
                acc[j].x += s * w.x; acc[j].y += s * w.y; acc[j].z += s * w.z; acc[j].w += s * w.w; }
            w = Wt24[(k4 * 4 + 3) * 128 + oq];
            #pragma unroll
            for (int j = 0; j < 8; ++j) { float s = sv[j].w;
                acc[j].x += s * w.x; acc[j].y += s * w.y; acc[j].z += s * w.z; acc[j].w += s * w.w; }
        }

        const float4 bv = *(const float4*)(bt2 + o);
        #pragma unroll
        for (int j = 0; j < 8; ++j) {
            if (b0 + j < BATCH) {
                float4 r;
                r.x = acc[j].x + bv.x; r.y = acc[j].y + bv.y;
                r.z = acc[j].z + bv.z; r.w = acc[j].w + bv.w;
                *(float4*)(out + (long)(b0 + j) * 1024 + o) = r;
            }
        }
    }
}

extern "C" void kernel_launch(void* const* d_in, const int* in_sizes, int n_in,
                              void* d_out, int out_size, void* d_ws, size_t ws_size,
                              hipStream_t stream)
{
    const float* self_vecs = (const float*)d_in[0];
    const float* neigh     = (const float*)d_in[1];
    const float* W1        = (const float*)d_in[2];
    const float* b1        = (const float*)d_in[3];
    const float* Wt1       = (const float*)d_in[4];
    const float* bt1       = (const float*)d_in[5];
    const float* Wt2       = (const float*)d_in[6];
    const float* bt2       = (const float*)d_in[7];
    float* out = (float*)d_out;

    dim3 grid(NBLK_NEIGH + NBLK_SELF);
    dim3 block(256);
    fused_aggr<<<grid, block, 0, stream>>>(self_vecs, neigh, W1, b1, Wt1, bt1, Wt2, bt2, out);
}